// Round 7
// baseline (39.726 us; speedup 1.0000x reference)
//
#include <hip/hip_runtime.h>
#include <stdint.h>

typedef __bf16 bf16x8 __attribute__((ext_vector_type(8)));
typedef float f32x4 __attribute__((ext_vector_type(4)));

constexpr int NP   = 256;   // n_patches
constexpr int DM   = 1024;  // d_model
constexpr int PRED = 720;
constexpr int P0   = 233;   // first contributing patch
constexpr int TMIN = 7504;  // total_len - PRED

// Single fused kernel: one block per batch; 512 thr = 8 waves = (ks 0..3) x (m 0..1).
// K in 4 quarters of 256, A double-buffered in LDS via global_load_lds (1 KB
// contiguous per instr), XOR-swizzled both sides (rule 21): byte ^= (row&7)<<4.
// B loaded fp32 from W (L2-resident) per step, converted inline (transient regs).
// After K-loop, LDS re-aliased as red[4][32][68]; fold writes out[b][0:720].
__global__ __launch_bounds__(512) void ph_fused(
    const float* __restrict__ x,     // [512][256][1024]
    const float* __restrict__ W,     // [64][1024] fp32
    const float* __restrict__ bias,  // [64]
    float* __restrict__ out)         // [512][720]
{
    __shared__ __align__(16) char smem[47104];

    const int b    = blockIdx.x;
    const int tid  = threadIdx.x;
    const int lane = tid & 63;
    const int wave = tid >> 6;        // 0..7
    const int r16  = lane & 15;
    const int kgrp = lane >> 4;
    const int m    = wave & 1;        // M-tile (16 patches)
    const int ks   = wave >> 1;       // K-sub window (64 per quarter)

    int row = m * 16 + r16;           // patch row 0..31; clamp pad rows
    if (row > 22) row = 22;
    const int swzr = (row & 7) << 4;

    f32x4 acc[4];
    #pragma unroll
    for (int n = 0; n < 4; ++n) acc[n] = (f32x4){0.f, 0.f, 0.f, 0.f};

    const char* xbase = (const char*)(x + ((size_t)b * NP + P0) * DM);

    auto stage = [&](int q, int buf) {
        for (int r = wave; r < 23; r += 8) {
            const char* src = xbase + (size_t)r * 4096 + q * 1024
                            + ((lane * 16) ^ ((r & 7) << 4));   // pre-swizzled source
            char* dst = smem + buf * 23552 + r * 1024;          // linear dest
            __builtin_amdgcn_global_load_lds(
                (const __attribute__((address_space(1))) uint32_t*)src,
                (__attribute__((address_space(3))) uint32_t*)dst, 16, 0, 0);
        }
    };

    stage(0, 0);
    asm volatile("s_waitcnt vmcnt(0)" ::: "memory");
    __syncthreads();

    for (int q = 0; q < 4; ++q) {
        const int buf = q & 1;
        if (q < 3) stage(q + 1, buf ^ 1);      // async prefetch next quarter

        const char* arow = smem + buf * 23552 + row * 1024;
        #pragma unroll
        for (int st = 0; st < 2; ++st) {
            const int koff = ks * 256 + st * 128 + kgrp * 32;   // byte off in quarter
            const f32x4 a0 = *(const f32x4*)(arow + ((koff     ) ^ swzr));
            const f32x4 a1 = *(const f32x4*)(arow + ((koff + 16) ^ swzr));
            bf16x8 af;
            af[0]=(__bf16)a0[0]; af[1]=(__bf16)a0[1]; af[2]=(__bf16)a0[2]; af[3]=(__bf16)a0[3];
            af[4]=(__bf16)a1[0]; af[5]=(__bf16)a1[1]; af[6]=(__bf16)a1[2]; af[7]=(__bf16)a1[3];

            const int kkd = q * 256 + ks * 64 + st * 32 + kgrp * 8;  // elem k for B
            #pragma unroll
            for (int n = 0; n < 4; ++n) {
                const float* wr = W + (size_t)(n * 16 + r16) * DM + kkd;
                const float4 b0 = *(const float4*)(wr);
                const float4 b1 = *(const float4*)(wr + 4);
                bf16x8 bf;
                bf[0]=(__bf16)b0.x; bf[1]=(__bf16)b0.y; bf[2]=(__bf16)b0.z; bf[3]=(__bf16)b0.w;
                bf[4]=(__bf16)b1.x; bf[5]=(__bf16)b1.y; bf[6]=(__bf16)b1.z; bf[7]=(__bf16)b1.w;
                acc[n] = __builtin_amdgcn_mfma_f32_16x16x32_bf16(af, bf, acc[n], 0, 0, 0);
            }
        }
        asm volatile("s_waitcnt vmcnt(0)" ::: "memory");
        __syncthreads();
    }

    // ---- reduce 4 K-subs + fold (alias smem as red[4][32][68]) ----
    float (*red)[32][68] = (float (*)[32][68])smem;

    // D layout (m89): row(patch) = m*16 + kgrp*4 + reg, col(j) = n*16 + r16.
    #pragma unroll
    for (int n = 0; n < 4; ++n)
        #pragma unroll
        for (int r = 0; r < 4; ++r)
            red[ks][m * 16 + kgrp * 4 + r][n * 16 + r16] = acc[n][r];

    __syncthreads();

    const int rr = tid >> 4;            // 0..31
    const int j0 = (tid & 15) * 4;      // 0..60
    f32x4 zs;
    #pragma unroll
    for (int qq = 0; qq < 4; ++qq) {
        float s = 0.f;
        #pragma unroll
        for (int w = 0; w < 4; ++w) s += red[w][rr][j0 + qq];
        zs[qq] = s;
    }
    __syncthreads();
    #pragma unroll
    for (int qq = 0; qq < 4; ++qq) red[0][rr][j0 + qq] = zs[qq];
    __syncthreads();

    // fold: t = o + TMIN; hi patch = t>>5 (j = t&31), lo patch = hi-1 (j+32)
    for (int o = tid; o < PRED; o += 512) {
        const int t  = o + TMIN;
        const int ph = t >> 5;          // 234..256
        const int j  = t & 31;
        float v = red[0][ph - 1 - P0][j + 32] + bias[j + 32];
        if (ph <= 255) v = (v + red[0][ph - P0][j] + bias[j]) * 0.5f;
        out[(size_t)b * PRED + o] = v;
    }
}

extern "C" void kernel_launch(void* const* d_in, const int* in_sizes, int n_in,
                              void* d_out, int out_size, void* d_ws, size_t ws_size,
                              hipStream_t stream) {
    const float* x    = (const float*)d_in[0];
    const float* W    = (const float*)d_in[1];
    const float* bias = (const float*)d_in[2];
    float* out = (float*)d_out;

    ph_fused<<<dim3(512), dim3(512), 0, stream>>>(x, W, bias, out);
}

// Round 8
// 30.763 us; speedup vs baseline: 1.2914x; 1.2914x over previous
//
#include <hip/hip_runtime.h>
#include <stdint.h>

typedef __bf16 bf16x8 __attribute__((ext_vector_type(8)));
typedef float f32x4 __attribute__((ext_vector_type(4)));

constexpr int NP   = 256;   // n_patches
constexpr int DM   = 1024;  // d_model
constexpr int PRED = 720;
constexpr int P0   = 233;   // first contributing patch
constexpr int TMIN = 7504;  // total_len - PRED

// ---- W fp32 -> bf16 (once per launch, into d_ws) ----
__global__ __launch_bounds__(256) void wconv(const float* __restrict__ W,
                                             __bf16* __restrict__ Wb) {
    const int i = (blockIdx.x * 256 + threadIdx.x) * 4;
    const float4 v = *(const float4*)(W + i);
    __bf16 o[4] = {(__bf16)v.x, (__bf16)v.y, (__bf16)v.z, (__bf16)v.w};
    *(short4*)(Wb + i) = *(short4*)o;
}

// One block per batch; 512 thr = 8 waves = (ks 0..3) x (m 0..1).
// K in 4 quarters of 256, A double-buffered in LDS via global_load_lds,
// XOR-swizzled both sides: byte ^= (row&7)<<4.
// DE-CAMPING vs R6: per-block quarter rotation (q = q0 + b mod 4) and
// per-block row-issue rotation so concurrent blocks don't hit addresses
// at lockstep 1 MiB stride.
__global__ __launch_bounds__(512) void ph_fused(
    const float*  __restrict__ x,     // [512][256][1024]
    const __bf16* __restrict__ Wb,    // [64][1024] bf16 (ws)
    const float*  __restrict__ bias,  // [64]
    float* __restrict__ out)          // [512][720]
{
    __shared__ __align__(16) char smem[47104];

    const int b    = blockIdx.x;
    const int tid  = threadIdx.x;
    const int lane = tid & 63;
    const int wave = tid >> 6;        // 0..7
    const int r16  = lane & 15;
    const int kgrp = lane >> 4;
    const int m    = wave & 1;        // M-tile (16 patches)
    const int ks   = wave >> 1;       // K-sub window (64 per quarter)

    const int qrot = b & 3;           // per-block K-quarter phase
    const int rrot = (b * 7) % 23;    // per-block row issue phase

    int row = m * 16 + r16;           // patch row 0..31; clamp pad rows
    if (row > 22) row = 22;
    const int swzr = (row & 7) << 4;

    f32x4 acc[4];
    #pragma unroll
    for (int n = 0; n < 4; ++n) acc[n] = (f32x4){0.f, 0.f, 0.f, 0.f};

    const char* xbase = (const char*)(x + ((size_t)b * NP + P0) * DM);

    auto stage = [&](int q, int buf) {
        for (int r0 = wave; r0 < 23; r0 += 8) {
            int r = r0 + rrot; if (r >= 23) r -= 23;            // issue-order rotate
            const char* src = xbase + (size_t)r * 4096 + q * 1024
                            + ((lane * 16) ^ ((r & 7) << 4));   // pre-swizzled source
            char* dst = smem + buf * 23552 + r * 1024;          // linear dest
            __builtin_amdgcn_global_load_lds(
                (const __attribute__((address_space(1))) uint32_t*)src,
                (__attribute__((address_space(3))) uint32_t*)dst, 16, 0, 0);
        }
    };

    stage(qrot, 0);
    asm volatile("s_waitcnt vmcnt(0)" ::: "memory");
    __syncthreads();

    for (int q0 = 0; q0 < 4; ++q0) {
        const int q   = (q0 + qrot) & 3;          // actual K-quarter
        const int buf = q0 & 1;
        if (q0 < 3) stage((q0 + 1 + qrot) & 3, buf ^ 1);   // async prefetch

        const char* arow = smem + buf * 23552 + row * 1024;
        #pragma unroll
        for (int st = 0; st < 2; ++st) {
            const int koff = ks * 256 + st * 128 + kgrp * 32;   // byte off in quarter
            const f32x4 a0 = *(const f32x4*)(arow + ((koff     ) ^ swzr));
            const f32x4 a1 = *(const f32x4*)(arow + ((koff + 16) ^ swzr));
            bf16x8 af;
            af[0]=(__bf16)a0[0]; af[1]=(__bf16)a0[1]; af[2]=(__bf16)a0[2]; af[3]=(__bf16)a0[3];
            af[4]=(__bf16)a1[0]; af[5]=(__bf16)a1[1]; af[6]=(__bf16)a1[2]; af[7]=(__bf16)a1[3];

            const int kkd = q * 256 + ks * 64 + st * 32 + kgrp * 8;  // elem k for B
            #pragma unroll
            for (int n = 0; n < 4; ++n) {
                const bf16x8 bf = *(const bf16x8*)(Wb + (size_t)(n * 16 + r16) * DM + kkd);
                acc[n] = __builtin_amdgcn_mfma_f32_16x16x32_bf16(af, bf, acc[n], 0, 0, 0);
            }
        }
        asm volatile("s_waitcnt vmcnt(0)" ::: "memory");
        __syncthreads();
    }

    // ---- reduce 4 K-subs + fold (alias smem as red[4][32][68]) ----
    float (*red)[32][68] = (float (*)[32][68])smem;

    // D layout (m89): row(patch) = m*16 + kgrp*4 + reg, col(j) = n*16 + r16.
    #pragma unroll
    for (int n = 0; n < 4; ++n)
        #pragma unroll
        for (int r = 0; r < 4; ++r)
            red[ks][m * 16 + kgrp * 4 + r][n * 16 + r16] = acc[n][r];

    __syncthreads();

    const int rr = tid >> 4;            // 0..31
    const int j0 = (tid & 15) * 4;      // 0..60
    f32x4 zs;
    #pragma unroll
    for (int qq = 0; qq < 4; ++qq) {
        float s = 0.f;
        #pragma unroll
        for (int w = 0; w < 4; ++w) s += red[w][rr][j0 + qq];
        zs[qq] = s;
    }
    __syncthreads();
    #pragma unroll
    for (int qq = 0; qq < 4; ++qq) red[0][rr][j0 + qq] = zs[qq];
    __syncthreads();

    // fold: t = o + TMIN; hi patch = t>>5 (j = t&31), lo patch = hi-1 (j+32)
    for (int o = tid; o < PRED; o += 512) {
        const int t  = o + TMIN;
        const int ph = t >> 5;          // 234..256
        const int j  = t & 31;
        float v = red[0][ph - 1 - P0][j + 32] + bias[j + 32];
        if (ph <= 255) v = (v + red[0][ph - P0][j] + bias[j]) * 0.5f;
        out[(size_t)b * PRED + o] = v;
    }
}

extern "C" void kernel_launch(void* const* d_in, const int* in_sizes, int n_in,
                              void* d_out, int out_size, void* d_ws, size_t ws_size,
                              hipStream_t stream) {
    const float* x    = (const float*)d_in[0];
    const float* W    = (const float*)d_in[1];
    const float* bias = (const float*)d_in[2];
    float*  out = (float*)d_out;
    __bf16* Wb  = (__bf16*)d_ws;   // 128 KB

    wconv<<<64, 256, 0, stream>>>(W, Wb);
    ph_fused<<<dim3(512), dim3(512), 0, stream>>>(x, Wb, bias, out);
}